// Round 8
// baseline (760.628 us; speedup 1.0000x reference)
//
#include <hip/hip_runtime.h>

#define BB 8
#define NN 4096
#define DD 64
#define SS 1024
#define KK 32
#define R2 0.04f
#define NCONS_BLK 248
#define NCONS_WAVE (NCONS_BLK * 8)

typedef float f32x2 __attribute__((ext_vector_type(2)));

// One DPP max stage: wv = max(wv, lanes-shifted wv). old = self -> invalid lanes
// contribute identity. row_shr:1,2,4,8 + row_bcast:15,31 -> lane 63 has wave max.
#define DPP_MAXF(wv, CTRL)                                                             \
    {                                                                                  \
        int _o = __builtin_amdgcn_update_dpp(__float_as_int(wv), __float_as_int(wv),   \
                                             CTRL, 0xf, 0xf, false);                   \
        (wv) = fmaxf((wv), __int_as_float(_o));                                        \
    }

// Fused producer/consumer kernel. 256 blocks x 512 thr.
// Occupancy control: launched with 4096 B of DYNAMIC shared memory, so the
// dispatch's group segment = 78848 (static) + 4096 = 82944 B > 160KiB/2.
// The HW allocator therefore places AT MOST ONE block per CU — producers own
// their CU exclusively (the R6/R7 interference fix, now compiler-proof).
// 256 blocks <= 256 CUs => all co-resident, spin-wait cannot deadlock.
extern __shared__ char dyn_pad[];   // sized at launch; never referenced further

__global__ __launch_bounds__(512) void fused_kernel(const float* __restrict__ xyz,
                                                    const float* __restrict__ points,
                                                    float* __restrict__ out,
                                                    int* __restrict__ fps_g,
                                                    int* __restrict__ progress) {
#pragma clang fp contract(off)
    __shared__ float4 sxyz[NN];                 // 64 KB (producer)
    __shared__ unsigned long long red[SS];      // 8 KB per-step slots (producer)
    __shared__ int sfar[SS];                    // 4 KB (producer)
    __shared__ int bbuf[8][KK];                 // 1 KB per-wave ball lists (consumer)

    const int tid  = threadIdx.x;
    const int wave = tid >> 6;
    const int lane = tid & 63;

    if (blockIdx.x < BB) {
        // ================= producer: FPS for batch b =================
        const int b = blockIdx.x;
        const float* xb = xyz + (size_t)b * NN * 3;

        for (int i = tid; i < SS; i += 512) red[i] = 0ull;   // slots: zero once

        // init: 96 contiguous bytes per lane (8 points x 3 floats) via 6x float4
        const float4* xb4 = (const float4*)(xb + tid * 24);
        const float4 q0 = xb4[0], q1 = xb4[1], q2 = xb4[2];
        const float4 q3 = xb4[3], q4 = xb4[4], q5 = xb4[5];

        f32x2 px[4], py[4], pz[4], dist[4];
        px[0] = (f32x2){q0.x, q0.w}; py[0] = (f32x2){q0.y, q1.x}; pz[0] = (f32x2){q0.z, q1.y};
        px[1] = (f32x2){q1.z, q2.y}; py[1] = (f32x2){q1.w, q2.z}; pz[1] = (f32x2){q2.x, q2.w};
        px[2] = (f32x2){q3.x, q3.w}; py[2] = (f32x2){q3.y, q4.x}; pz[2] = (f32x2){q3.z, q4.y};
        px[3] = (f32x2){q4.z, q5.y}; py[3] = (f32x2){q4.w, q5.z}; pz[3] = (f32x2){q5.x, q5.w};
#pragma unroll
        for (int jj = 0; jj < 4; ++jj) {
            const int i0 = tid * 8 + 2 * jj;
            sxyz[i0]     = make_float4(px[jj].x, py[jj].x, pz[jj].x, 0.0f);
            sxyz[i0 + 1] = make_float4(px[jj].y, py[jj].y, pz[jj].y, 0.0f);
            dist[jj] = (f32x2){1e10f, 1e10f};
        }
        __syncthreads();

        int far = 0;
        for (int t = 0; t < SS; ++t) {
            if (tid == 0) sfar[t] = far;         // scan emits pre-update carry
            const float4 c = sxyz[far];          // one ds_read_b128 (broadcast)
            const f32x2 cx2 = (f32x2){c.x, c.x}, cy2 = (f32x2){c.y, c.y},
                        cz2 = (f32x2){c.z, c.z};

            f32x2 nd[4];
#pragma unroll
            for (int jj = 0; jj < 4; ++jj) {
                // exact ref order: ((dx^2 + dy^2) + dz^2); contract(off) => no FMA
                const f32x2 dx = px[jj] - cx2;
                const f32x2 dy = py[jj] - cy2;
                const f32x2 dz = pz[jj] - cz2;
                const f32x2 d  = (dx * dx + dy * dy) + dz * dz;
                f32x2 m;
                m.x = fminf(dist[jj].x, d.x);    // fmin exact; order-independent
                m.y = fminf(dist[jj].y, d.y);
                dist[jj] = m;
                nd[jj] = m;
            }
            // per-lane max (tree; values non-negative, no NaN)
            const float bestv =
                fmaxf(fmaxf(fmaxf(nd[0].x, nd[0].y), fmaxf(nd[1].x, nd[1].y)),
                      fmaxf(fmaxf(nd[2].x, nd[2].y), fmaxf(nd[3].x, nd[3].y)));
            // smallest j achieving it (descending scan => first match wins)
            int localj = 0;
#pragma unroll
            for (int j = 7; j >= 0; --j) {
                const float v = (j & 1) ? nd[j >> 1].y : nd[j >> 1].x;
                if (v == bestv) localj = j;
            }

            // wave max via fused DPP f32 max; recover first-lane index via ballot+ffs
            float wv = bestv;
            DPP_MAXF(wv, 0x111);   // row_shr:1
            DPP_MAXF(wv, 0x112);   // row_shr:2
            DPP_MAXF(wv, 0x114);   // row_shr:4
            DPP_MAXF(wv, 0x118);   // row_shr:8
            DPP_MAXF(wv, 0x142);   // row_bcast:15
            DPP_MAXF(wv, 0x143);   // row_bcast:31
            const float maxw =
                __int_as_float(__builtin_amdgcn_readlane(__float_as_int(wv), 63));

            const unsigned long long hits = __ballot(bestv == maxw);
            const int L = __ffsll(hits) - 1;     // smallest lane == smallest global idx
            const int candv = tid * 8 + localj;  // global point index
            const int cand  = __builtin_amdgcn_readlane(candv, L);

            // leaders race into the per-step slot; u64 max == (max val, min index)
            if (lane == 0) {
                const unsigned long long p =
                    ((unsigned long long)__float_as_uint(maxw) << 32) | (unsigned)(~cand);
                atomicMax(&red[t], p);
            }
            __syncthreads();                     // the only barrier in the step
            far = (int)(~(unsigned)red[t]);      // broadcast ds_read_b64

            // publish a 32-step chunk; RELEASE store orders the fps_g stores
            if ((t & 31) == 31 && wave == 7) {
                const int c0 = t - 31;
                if (lane < 32) fps_g[b * SS + c0 + lane] = sfar[c0 + lane];
                if (lane == 0)
                    __hip_atomic_store(&progress[b], t + 1, __ATOMIC_RELEASE,
                                       __HIP_MEMORY_SCOPE_AGENT);
            }
        }
    } else {
        // ================= consumer: ball query + output assembly =================
        const int wid = (blockIdx.x - BB) * 8 + wave;   // 0..1983
        for (int g = wid; g < BB * SS; g += NCONS_WAVE) {
            const int b = g >> 10;               // SS == 1024
            const int s = g & (SS - 1);
            // gate: lane 0 polls relaxed (poison = negative), then one acquire fence
            if (lane == 0) {
                while (__hip_atomic_load(&progress[b], __ATOMIC_RELAXED,
                                         __HIP_MEMORY_SCOPE_AGENT) <= s)
                    __builtin_amdgcn_s_sleep(64);
            }
            __builtin_amdgcn_fence(__ATOMIC_ACQUIRE, "agent");
            const int qi = fps_g[g];

            const float* xb = xyz + (size_t)b * NN * 3;
            const float* pb = points + (size_t)b * NN * DD;
            const float qx = xb[qi * 3 + 0], qy = xb[qi * 3 + 1], qz = xb[qi * 3 + 2];
            const float qn = __fadd_rn(__fadd_rn(__fmul_rn(qx, qx), __fmul_rn(qy, qy)),
                                       __fmul_rn(qz, qz));

            int total = 0;
            for (int base = 0; base < NN && total < KK; base += 64) {
                const int n  = base + lane;
                const float px = xb[n * 3 + 0], py = xb[n * 3 + 1], pz = xb[n * 3 + 2];
                const float pn = __fadd_rn(__fadd_rn(__fmul_rn(px, px), __fmul_rn(py, py)),
                                           __fmul_rn(pz, pz));
                const float dt = __fadd_rn(__fadd_rn(__fmul_rn(qx, px), __fmul_rn(qy, py)),
                                           __fmul_rn(qz, pz));
                // exact ref order: d = (-2*dot) + |q|^2 + |p|^2
                const float d = __fadd_rn(__fadd_rn(__fmul_rn(-2.0f, dt), qn), pn);
                const bool hit = !(d > R2);      // include iff d <= r^2
                const unsigned long long mask = __ballot(hit);
                const int before = __popcll(mask & ((1ull << lane) - 1ull));
                const int pos = total + before;
                if (hit && pos < KK) bbuf[wave][pos] = n;
                total += (int)__popcll(mask);
            }
            // pad with first element (wave-synchronous LDS, no barrier needed)
            if (lane < KK) {
                const int v = (lane < total) ? bbuf[wave][lane] : bbuf[wave][0];
                bbuf[wave][lane] = v;
            }

            if (lane < 3) out[(size_t)g * 3 + lane] = xb[qi * 3 + lane];

            float* outp = out + (size_t)BB * SS * 3 + (size_t)g * (KK * 131);
            for (int c = lane; c < KK * 131; c += 64) {
                const int k = c / 131;
                const int j = c - k * 131;
                const int idx = bbuf[wave][k];
                float v;
                if (j < DD)          v = pb[idx * DD + j];
                else if (j < DD + 3) v = xb[idx * 3 + (j - DD)];
                else                 v = pb[qi * DD + (j - DD - 3)];   // anchor feat
                outp[c] = v;
            }
        }
    }
}

extern "C" void kernel_launch(void* const* d_in, const int* in_sizes, int n_in,
                              void* d_out, int out_size, void* d_ws, size_t ws_size,
                              hipStream_t stream) {
    const float* xyz    = (const float*)d_in[0];   // [B,N,3]
    const float* points = (const float*)d_in[1];   // [B,N,D]
    float* out = (float*)d_out;

    int* fps_g    = (int*)d_ws;                    // [B*S]
    int* progress = fps_g + BB * SS;               // [B] (poison 0xAA.. = negative)

    // 4096 B dynamic LDS: static 78848 + 4096 = 82944 > 81920 => 1 block/CU.
    fused_kernel<<<BB + NCONS_BLK, 512, 4096, stream>>>(xyz, points, out, fps_g,
                                                        progress);
}

// Round 9
// 739.151 us; speedup vs baseline: 1.0291x; 1.0291x over previous
//
#include <hip/hip_runtime.h>

#define BB 8
#define NN 4096
#define DD 64
#define SS 1024
#define KK 32
#define R2 0.04f

typedef float f32x2 __attribute__((ext_vector_type(2)));

// One DPP max stage: wv = max(wv, lanes-shifted wv). old = self -> invalid lanes
// contribute identity. row_shr:1,2,4,8 + row_bcast:15,31 -> lane 63 has wave max.
#define DPP_MAXF(wv, CTRL)                                                             \
    {                                                                                  \
        int _o = __builtin_amdgcn_update_dpp(__float_as_int(wv), __float_as_int(wv),   \
                                             CTRL, 0xf, 0xf, false);                   \
        (wv) = fmaxf((wv), __int_as_float(_o));                                        \
    }

// Redundant-FPS design: 256 blocks x 512 thr, one per CU (static LDS 82176 B >
// 160KiB/2 forces 1 block/CU in hardware). Block handles batch b = blk>>5 and
// group chunk cs = blk&31: it computes the FULL FPS for its batch (identical,
// deterministic work replicated across the 32 blocks of that batch — fminf and
// max are order-independent, LDS atomicMax result is order-invariant), then
// serves its own 32 groups (ball query + output) entirely from its own LDS.
// NO cross-block synchronization exists: no spin, no fences, no deadlock, and
// the FPS loop contains zero global-memory operations (the R8 publication tax).
__global__ __launch_bounds__(512) void fused_kernel(const float* __restrict__ xyz,
                                                    const float* __restrict__ points,
                                                    float* __restrict__ out) {
#pragma clang fp contract(off)
    __shared__ float4 sxyz[NN];                    // 64 KB {x,y,z,pad}
    __shared__ unsigned long long red[SS + 416];   // 11.25 KB (416 = LDS occupancy pad)
    __shared__ int sfar[SS];                       // 4 KB
    __shared__ int bbuf[8][KK];                    // 1 KB per-wave ball lists

    const int tid  = threadIdx.x;
    const int wave = tid >> 6;
    const int lane = tid & 63;
    const int b    = blockIdx.x >> 5;              // batch
    const int cs   = blockIdx.x & 31;              // group chunk within batch
    const float* xb = xyz + (size_t)b * NN * 3;
    const float* pb = points + (size_t)b * NN * DD;

    for (int i = tid; i < SS; i += 512) red[i] = 0ull;   // slots: zero once

    // ---- init: 96 contiguous bytes per lane (8 points x 3 floats) via 6x float4 ----
    const float4* xb4 = (const float4*)(xb + tid * 24);
    const float4 q0 = xb4[0], q1 = xb4[1], q2 = xb4[2];
    const float4 q3 = xb4[3], q4 = xb4[4], q5 = xb4[5];

    f32x2 px[4], py[4], pz[4], dist[4];
    px[0] = (f32x2){q0.x, q0.w}; py[0] = (f32x2){q0.y, q1.x}; pz[0] = (f32x2){q0.z, q1.y};
    px[1] = (f32x2){q1.z, q2.y}; py[1] = (f32x2){q1.w, q2.z}; pz[1] = (f32x2){q2.x, q2.w};
    px[2] = (f32x2){q3.x, q3.w}; py[2] = (f32x2){q3.y, q4.x}; pz[2] = (f32x2){q3.z, q4.y};
    px[3] = (f32x2){q4.z, q5.y}; py[3] = (f32x2){q4.w, q5.z}; pz[3] = (f32x2){q5.x, q5.w};
#pragma unroll
    for (int jj = 0; jj < 4; ++jj) {
        const int i0 = tid * 8 + 2 * jj;
        sxyz[i0]     = make_float4(px[jj].x, py[jj].x, pz[jj].x, 0.0f);
        sxyz[i0 + 1] = make_float4(px[jj].y, py[jj].y, pz[jj].y, 0.0f);
        dist[jj] = (f32x2){1e10f, 1e10f};
    }
    __syncthreads();

    // ================= FPS (replicated per block; zero global ops) =================
    int far = 0;
    for (int t = 0; t < SS; ++t) {
        if (tid == 0) sfar[t] = far;             // scan emits pre-update carry
        const float4 c = sxyz[far];              // one ds_read_b128 (broadcast)
        const f32x2 cx2 = (f32x2){c.x, c.x}, cy2 = (f32x2){c.y, c.y},
                    cz2 = (f32x2){c.z, c.z};

        f32x2 nd[4];
#pragma unroll
        for (int jj = 0; jj < 4; ++jj) {
            // exact ref order: ((dx^2 + dy^2) + dz^2); contract(off) => no FMA
            const f32x2 dx = px[jj] - cx2;
            const f32x2 dy = py[jj] - cy2;
            const f32x2 dz = pz[jj] - cz2;
            const f32x2 d  = (dx * dx + dy * dy) + dz * dz;
            f32x2 m;
            m.x = fminf(dist[jj].x, d.x);        // fmin exact; order-independent
            m.y = fminf(dist[jj].y, d.y);
            dist[jj] = m;
            nd[jj] = m;
        }
        // per-lane max (tree; values non-negative, no NaN)
        const float bestv =
            fmaxf(fmaxf(fmaxf(nd[0].x, nd[0].y), fmaxf(nd[1].x, nd[1].y)),
                  fmaxf(fmaxf(nd[2].x, nd[2].y), fmaxf(nd[3].x, nd[3].y)));
        // smallest j achieving it (descending scan => first match wins)
        int localj = 0;
#pragma unroll
        for (int j = 7; j >= 0; --j) {
            const float v = (j & 1) ? nd[j >> 1].y : nd[j >> 1].x;
            if (v == bestv) localj = j;
        }

        // wave max via fused DPP f32 max; recover first-lane index via ballot+ffs
        float wv = bestv;
        DPP_MAXF(wv, 0x111);   // row_shr:1
        DPP_MAXF(wv, 0x112);   // row_shr:2
        DPP_MAXF(wv, 0x114);   // row_shr:4
        DPP_MAXF(wv, 0x118);   // row_shr:8
        DPP_MAXF(wv, 0x142);   // row_bcast:15
        DPP_MAXF(wv, 0x143);   // row_bcast:31
        const float maxw =
            __int_as_float(__builtin_amdgcn_readlane(__float_as_int(wv), 63));

        const unsigned long long hits = __ballot(bestv == maxw);
        const int L = __ffsll(hits) - 1;         // smallest lane == smallest global idx
        const int candv = tid * 8 + localj;      // global point index
        const int cand  = __builtin_amdgcn_readlane(candv, L);

        // leaders race into the per-step slot; u64 max == (max val, min index);
        // final value is order-invariant => identical across replicated blocks
        if (lane == 0) {
            const unsigned long long p =
                ((unsigned long long)__float_as_uint(maxw) << 32) | (unsigned)(~cand);
            atomicMax(&red[t], p);
        }
        __syncthreads();                         // the only barrier in the step
        far = (int)(~(unsigned)red[t]);          // broadcast ds_read_b64
    }
    // sfar[] fully visible: each sfar[t] write precedes that step's barrier.

    // ============ this block's 32 groups: ball query + output, all from LDS ============
#pragma unroll
    for (int i = 0; i < 4; ++i) {
        const int s  = cs * 32 + wave * 4 + i;   // group within batch
        const int g  = b * SS + s;               // flat group id
        const int qi = sfar[s];
        const float4 q = sxyz[qi];
        const float qn = __fadd_rn(__fadd_rn(__fmul_rn(q.x, q.x), __fmul_rn(q.y, q.y)),
                                   __fmul_rn(q.z, q.z));

        int total = 0;
        for (int base = 0; base < NN && total < KK; base += 64) {
            const int n = base + lane;
            const float4 p = sxyz[n];            // ds_read_b128; values == global xyz
            const float pn = __fadd_rn(__fadd_rn(__fmul_rn(p.x, p.x), __fmul_rn(p.y, p.y)),
                                       __fmul_rn(p.z, p.z));
            const float dt = __fadd_rn(__fadd_rn(__fmul_rn(q.x, p.x), __fmul_rn(q.y, p.y)),
                                       __fmul_rn(q.z, p.z));
            // exact ref order: d = (-2*dot) + |q|^2 + |p|^2
            const float d = __fadd_rn(__fadd_rn(__fmul_rn(-2.0f, dt), qn), pn);
            const bool hit = !(d > R2);          // include iff d <= r^2
            const unsigned long long mask = __ballot(hit);
            const int before = __popcll(mask & ((1ull << lane) - 1ull));
            const int pos = total + before;
            if (hit && pos < KK) bbuf[wave][pos] = n;
            total += (int)__popcll(mask);
        }
        // pad with first element (wave-synchronous LDS, no barrier needed)
        if (lane < KK) {
            const int v = (lane < total) ? bbuf[wave][lane] : bbuf[wave][0];
            bbuf[wave][lane] = v;
        }

        // new_xyz
        if (lane < 3)
            out[(size_t)g * 3 + lane] = (lane == 0) ? q.x : (lane == 1) ? q.y : q.z;

        // anchor feature columns this lane is responsible for (same for all k)
        const float a1 = (lane >= 3) ? pb[qi * DD + (lane - 3)] : 0.0f;  // cols 67..127
        const float a2 = (lane < 3) ? pb[qi * DD + (61 + lane)] : 0.0f;  // cols 128..130

        float* outp = out + (size_t)BB * SS * 3 + (size_t)g * (KK * 131);
        for (int k = 0; k < KK; ++k) {
            const int idx = bbuf[wave][k];
            const float4 pi = sxyz[idx];
            outp[k * 131 + lane] = pb[idx * DD + lane];                    // cols 0..63
            const float v1 = (lane == 0) ? pi.x
                           : (lane == 1) ? pi.y
                           : (lane == 2) ? pi.z
                                         : a1;                             // cols 64..127
            outp[k * 131 + 64 + lane] = v1;
            if (lane < 3) outp[k * 131 + 128 + lane] = a2;                 // cols 128..130
        }
    }
}

extern "C" void kernel_launch(void* const* d_in, const int* in_sizes, int n_in,
                              void* d_out, int out_size, void* d_ws, size_t ws_size,
                              hipStream_t stream) {
    const float* xyz    = (const float*)d_in[0];   // [B,N,3]
    const float* points = (const float*)d_in[1];   // [B,N,D]
    float* out = (float*)d_out;

    fused_kernel<<<BB * 32, 512, 0, stream>>>(xyz, points, out);
}